// Round 3
// baseline (120.861 us; speedup 1.0000x reference)
//
#include <hip/hip_runtime.h>

// GeodesicConv via counting-sort by filter bin.
//
// out[p,d] = sum_c feat[p,c] * filters[bin(p)][c][d] + bias[d], 40 bins.
//
// K1: per-point bin + per-block(1024) LDS histogram -> hist[nblk][40]
// K2: single block: scan hist -> blkoff[nblk][40] (global segment offsets)
// K3: recompute bin, LDS-atomic rank -> sorted_pk[pos] = idx | (bin<<20)
// K4: wave = 64 consecutive sorted positions (same bin except <=39 boundary
//     waves). lane = point. W rows are wave-uniform -> SGPR (s_load), matvec
//     is v_fmac(acc_vgpr, s_row[d], f_vgpr[c]) -- zero per-point W traffic.
//     while(rem)/readfirstlane loop handles mixed-bin waves exactly.
//
// Bin math identical to the round-1 bit-exact version: trunc(r*5.0f),
// trunc((a*8.0f)/TWO_PI_F), IEEE f32, no fast-math assumptions.

#define NBINS 40
#define K1_THREADS 1024
#define MAX_NBLK 128

__device__ __forceinline__ int bin_of(float2 rc) {
    const float TWO_PI_F = (float)(2.0 * 3.14159);
    int ri = (int)(rc.x * 5.0f);
    ri = min(max(ri, 0), 4);
    int oi = (int)((rc.y * 8.0f) / TWO_PI_F);
    oi = min(max(oi, 0), 7);
    return ri * 8 + oi;
}

__global__ __launch_bounds__(K1_THREADS)
void k_hist(const float2* __restrict__ coords, int* __restrict__ hist, int npts) {
    __shared__ int h[NBINS];
    const int tid = threadIdx.x;
    if (tid < NBINS) h[tid] = 0;
    __syncthreads();
    const int p = blockIdx.x * K1_THREADS + tid;
    if (p < npts) atomicAdd(&h[bin_of(coords[p])], 1);
    __syncthreads();
    if (tid < NBINS) hist[blockIdx.x * NBINS + tid] = h[tid];
}

__global__ __launch_bounds__(K1_THREADS)
void k_scan(const int* __restrict__ hist, int* __restrict__ blkoff, int nblk) {
    __shared__ int lh[MAX_NBLK * NBINS];
    __shared__ int base[NBINS];
    const int tid = threadIdx.x;
    for (int i = tid; i < nblk * NBINS; i += K1_THREADS) lh[i] = hist[i];
    __syncthreads();
    if (tid < NBINS) {                 // per-bin exclusive scan over blocks
        int s = 0;
        for (int k = 0; k < nblk; ++k) { int v = lh[k * NBINS + tid]; lh[k * NBINS + tid] = s; s += v; }
        base[tid] = s;                 // bin total
    }
    __syncthreads();
    if (tid == 0) {                    // exclusive scan over bins
        int s = 0;
        for (int b = 0; b < NBINS; ++b) { int v = base[b]; base[b] = s; s += v; }
    }
    __syncthreads();
    if (tid < NBINS) for (int k = 0; k < nblk; ++k) lh[k * NBINS + tid] += base[tid];
    __syncthreads();
    for (int i = tid; i < nblk * NBINS; i += K1_THREADS) blkoff[i] = lh[i];
}

__global__ __launch_bounds__(K1_THREADS)
void k_scatter(const float2* __restrict__ coords, const int* __restrict__ blkoff,
               int* __restrict__ sorted_pk, int npts) {
    __shared__ int off[NBINS];
    __shared__ int cnt[NBINS];
    const int tid = threadIdx.x;
    if (tid < NBINS) { off[tid] = blkoff[blockIdx.x * NBINS + tid]; cnt[tid] = 0; }
    __syncthreads();
    const int p = blockIdx.x * K1_THREADS + tid;
    if (p < npts) {
        const int b = bin_of(coords[p]);
        const int r = atomicAdd(&cnt[b], 1);
        sorted_pk[off[b] + r] = p | (b << 20);
    }
}

__global__ __launch_bounds__(256)
void k_gemm(const float* __restrict__ feat, const float* __restrict__ filt,
            const float* __restrict__ bias, const int* __restrict__ sorted_pk,
            float* __restrict__ out, int npts) {
    const int tid  = threadIdx.x;
    const int wave = tid >> 6;
    const int lane = tid & 63;
    const int pos  = (blockIdx.x * 4 + wave) * 64 + lane;   // npts % 256 == 0

    const int pk  = sorted_pk[pos];
    const int idx = pk & 0xFFFFF;
    const int b   = pk >> 20;

    // lane's features -> 32 VGPRs (static-indexed via full unroll)
    const float4* fp = reinterpret_cast<const float4*>(feat + (size_t)idx * 32);
    float f[32];
    #pragma unroll
    for (int g = 0; g < 8; ++g) {
        float4 v = fp[g];
        f[g * 4 + 0] = v.x; f[g * 4 + 1] = v.y; f[g * 4 + 2] = v.z; f[g * 4 + 3] = v.w;
    }

    float acc[32];
    #pragma unroll
    for (int d = 0; d < 32; ++d) acc[d] = bias[d];          // uniform s_load

    unsigned long long rem = __ballot(1);                    // all 64 lanes
    while (rem) {
        const int src = (int)__ffsll((long long)rem) - 1;
        const int bb  = __shfl(b, src);                      // wave-uniform bin
        const unsigned long long m = __ballot(b == bb);
        rem &= ~m;
        const bool act = (b == bb);
        const float* __restrict__ W = filt + (size_t)bb * 1024;
        #pragma unroll
        for (int c = 0; c < 32; ++c) {
            const float fc = act ? f[c] : 0.0f;              // exact: adds 0 when inactive
            #pragma unroll
            for (int d = 0; d < 32; ++d)
                acc[d] = fmaf(fc, W[c * 32 + d], acc[d]);    // W: uniform -> SGPR row
        }
    }

    float4* op = reinterpret_cast<float4*>(out + (size_t)idx * 32);
    #pragma unroll
    for (int g = 0; g < 8; ++g)
        op[g] = make_float4(acc[g * 4 + 0], acc[g * 4 + 1], acc[g * 4 + 2], acc[g * 4 + 3]);
}

extern "C" void kernel_launch(void* const* d_in, const int* in_sizes, int n_in,
                              void* d_out, int out_size, void* d_ws, size_t ws_size,
                              hipStream_t stream) {
    const float*  feat   = (const float*)d_in[0];
    const float2* coords = (const float2*)d_in[1];
    const float*  filt   = (const float*)d_in[2];
    const float*  bias   = (const float*)d_in[3];
    float* out = (float*)d_out;

    const int npts = in_sizes[0] / 32;                       // 131072
    const int nblk = (npts + K1_THREADS - 1) / K1_THREADS;   // 128

    int* sorted_pk = (int*)d_ws;                             // npts ints
    int* hist      = sorted_pk + npts;                       // nblk*40
    int* blkoff    = hist + nblk * NBINS;                    // nblk*40

    k_hist   <<<nblk, K1_THREADS, 0, stream>>>(coords, hist, npts);
    k_scan   <<<1,    K1_THREADS, 0, stream>>>(hist, blkoff, nblk);
    k_scatter<<<nblk, K1_THREADS, 0, stream>>>(coords, blkoff, sorted_pk, npts);
    k_gemm   <<<npts / 256, 256,  0, stream>>>(feat, filt, bias, sorted_pk, out, npts);
}

// Round 4
// 94.590 us; speedup vs baseline: 1.2777x; 1.2777x over previous
//
#include <hip/hip_runtime.h>

// GeodesicConv via counting-sort by filter bin, W broadcast from LDS.
//
// out[p,d] = sum_c feat[p,c] * filters[bin(p)][c][d] + bias[d], 40 bins.
//
// K1 k_hist:    bin each point (cache as u8), per-block(1024) LDS histogram.
// K2 k_scan:    wave-parallel 2-level exclusive scan -> blkoff[nblk][40].
// K3 k_scatter: LDS-atomic rank -> sorted_pk[pos] = idx | (bin<<20).
// K4 k_gemm:    block = 256 sorted points. Sorted order => block spans
//               nb = b_last-b_first+1 bins (≈1-2; ≤4 with huge margin since
//               bin segments average 3277 pts). Stage those bins' W into LDS
//               (16 KB); inner loop = ds_read_b128 at wave-uniform address
//               (broadcast, conflict-free, independent -> pipelines) feeding
//               v_fmac. Replaces round-3's serializing s_load W stream.
//               while(rem)/ballot loop keeps mixed-bin waves exact.
//
// Bin math bit-exact vs numpy f32: trunc(r*5.0f), trunc((a*8.0f)/TWO_PI_F).

#define NBINS 40
#define NB_MAX 4
#define PPB 256
#define MAX_NBLK 128

__device__ __forceinline__ int bin_of(float2 rc) {
    const float TWO_PI_F = (float)(2.0 * 3.14159);
    int ri = (int)(rc.x * 5.0f);
    ri = min(max(ri, 0), 4);
    int oi = (int)((rc.y * 8.0f) / TWO_PI_F);
    oi = min(max(oi, 0), 7);
    return ri * 8 + oi;
}

__global__ __launch_bounds__(1024)
void k_hist(const float2* __restrict__ coords, int* __restrict__ hist,
            unsigned char* __restrict__ bins_u8, int npts) {
    __shared__ int h[NBINS];
    const int tid = threadIdx.x;
    if (tid < NBINS) h[tid] = 0;
    __syncthreads();
    const int p = blockIdx.x * 1024 + tid;
    if (p < npts) {
        const int b = bin_of(coords[p]);
        bins_u8[p] = (unsigned char)b;
        atomicAdd(&h[b], 1);
    }
    __syncthreads();
    if (tid < NBINS) hist[blockIdx.x * NBINS + tid] = h[tid];
}

__global__ __launch_bounds__(1024)
void k_scan(const int* __restrict__ hist, int* __restrict__ blkoff, int nblk) {
    __shared__ int lh[MAX_NBLK * NBINS];
    __shared__ int btot[NBINS];
    __shared__ int base[NBINS];
    const int tid  = threadIdx.x;
    const int wave = tid >> 6;
    const int lane = tid & 63;
    for (int i = tid; i < nblk * NBINS; i += 1024) lh[i] = hist[i];
    __syncthreads();
    // per-bin exclusive scan over 128 blocks: one wave per bin (wave-parallel)
    for (int b = wave; b < NBINS; b += 16) {
        int v0 = lh[lane * NBINS + b];          // blocks 0..63
        int v1 = lh[(64 + lane) * NBINS + b];   // blocks 64..127
        #pragma unroll
        for (int off = 1; off < 64; off <<= 1) { int t = __shfl_up(v0, off); if (lane >= off) v0 += t; }
        const int tot0 = __shfl(v0, 63);
        #pragma unroll
        for (int off = 1; off < 64; off <<= 1) { int t = __shfl_up(v1, off); if (lane >= off) v1 += t; }
        const int total = __shfl(v1, 63) + tot0;
        int e0 = __shfl_up(v0, 1); if (lane == 0) e0 = 0;
        int e1 = __shfl_up(v1, 1); if (lane == 0) e1 = 0;
        e1 += tot0;
        lh[lane * NBINS + b] = e0;
        lh[(64 + lane) * NBINS + b] = e1;
        if (lane == 0) btot[b] = total;
    }
    __syncthreads();
    if (wave == 0) {                            // exclusive scan over 40 bin totals
        int v = (lane < NBINS) ? btot[lane] : 0;
        #pragma unroll
        for (int off = 1; off < 64; off <<= 1) { int t = __shfl_up(v, off); if (lane >= off) v += t; }
        int e = __shfl_up(v, 1); if (lane == 0) e = 0;
        if (lane < NBINS) base[lane] = e;
    }
    __syncthreads();
    for (int i = tid; i < nblk * NBINS; i += 1024) {
        const int b = i - (i / NBINS) * NBINS;
        blkoff[i] = lh[i] + base[b];
    }
}

__global__ __launch_bounds__(1024)
void k_scatter(const unsigned char* __restrict__ bins_u8, const int* __restrict__ blkoff,
               int* __restrict__ sorted_pk, int npts) {
    __shared__ int off[NBINS];
    __shared__ int cnt[NBINS];
    const int tid = threadIdx.x;
    if (tid < NBINS) { off[tid] = blkoff[blockIdx.x * NBINS + tid]; cnt[tid] = 0; }
    __syncthreads();
    const int p = blockIdx.x * 1024 + tid;
    if (p < npts) {
        const int b = (int)bins_u8[p];
        const int r = atomicAdd(&cnt[b], 1);
        sorted_pk[off[b] + r] = p | (b << 20);
    }
}

#define GEMM_BODY(W4EXPR)                                                     \
    unsigned long long rem = __ballot(1);                                     \
    while (rem) {                                                             \
        const int src = (int)__ffsll((long long)rem) - 1;                     \
        const int bb  = __shfl(b, src);                                       \
        const unsigned long long m = __ballot(b == bb);                       \
        rem &= ~m;                                                            \
        const bool act = (b == bb);                                           \
        const float4* __restrict__ W4 = (W4EXPR);                             \
        _Pragma("unroll")                                                     \
        for (int c = 0; c < 32; ++c) {                                        \
            const float fc = act ? f[c] : 0.0f;                               \
            _Pragma("unroll")                                                 \
            for (int d4 = 0; d4 < 8; ++d4) {                                  \
                const float4 w = W4[c * 8 + d4];                              \
                acc[d4 * 4 + 0] = fmaf(fc, w.x, acc[d4 * 4 + 0]);             \
                acc[d4 * 4 + 1] = fmaf(fc, w.y, acc[d4 * 4 + 1]);             \
                acc[d4 * 4 + 2] = fmaf(fc, w.z, acc[d4 * 4 + 2]);             \
                acc[d4 * 4 + 3] = fmaf(fc, w.w, acc[d4 * 4 + 3]);             \
            }                                                                 \
        }                                                                     \
    }

__global__ __launch_bounds__(256)
void k_gemm(const float* __restrict__ feat, const float* __restrict__ filt,
            const float* __restrict__ bias, const int* __restrict__ sorted_pk,
            float* __restrict__ out) {
    __shared__ float4 Wl[NB_MAX * 256];         // up to 4 bins x 4 KB = 16 KB
    const int tid     = threadIdx.x;
    const int blkbase = blockIdx.x * PPB;

    const int pk  = sorted_pk[blkbase + tid];
    const int idx = pk & 0xFFFFF;
    const int b   = pk >> 20;

    const int b0 = sorted_pk[blkbase] >> 20;            // sorted => block bins
    const int b1 = sorted_pk[blkbase + PPB - 1] >> 20;  //   span [b0, b1]
    const int nb = b1 - b0 + 1;

    const float4* __restrict__ filt4 = reinterpret_cast<const float4*>(filt);
    if (nb <= NB_MAX) {
        for (int i = tid; i < nb * 256; i += 256) Wl[i] = filt4[b0 * 256 + i];
    }
    __syncthreads();

    const float4* fp = reinterpret_cast<const float4*>(feat + (size_t)idx * 32);
    float f[32];
    #pragma unroll
    for (int g = 0; g < 8; ++g) {
        const float4 v = fp[g];
        f[g * 4 + 0] = v.x; f[g * 4 + 1] = v.y; f[g * 4 + 2] = v.z; f[g * 4 + 3] = v.w;
    }

    float acc[32];
    #pragma unroll
    for (int d = 0; d < 32; ++d) acc[d] = bias[d];      // uniform s_load

    if (nb <= NB_MAX) {             // hot path: W broadcast from LDS
        GEMM_BODY(&Wl[(bb - b0) * 256])
    } else {                        // never in practice (segments >> PPB)
        GEMM_BODY(&filt4[(size_t)bb * 256])
    }

    float4* op = reinterpret_cast<float4*>(out + (size_t)idx * 32);
    #pragma unroll
    for (int g = 0; g < 8; ++g)
        op[g] = make_float4(acc[g * 4 + 0], acc[g * 4 + 1], acc[g * 4 + 2], acc[g * 4 + 3]);
}

extern "C" void kernel_launch(void* const* d_in, const int* in_sizes, int n_in,
                              void* d_out, int out_size, void* d_ws, size_t ws_size,
                              hipStream_t stream) {
    const float*  feat   = (const float*)d_in[0];
    const float2* coords = (const float2*)d_in[1];
    const float*  filt   = (const float*)d_in[2];
    const float*  bias   = (const float*)d_in[3];
    float* out = (float*)d_out;

    const int npts = in_sizes[0] / 32;                   // 131072
    const int nblk = (npts + 1023) / 1024;               // 128

    int* sorted_pk           = (int*)d_ws;               // npts
    int* hist                = sorted_pk + npts;         // nblk*40
    int* blkoff              = hist + nblk * NBINS;      // nblk*40
    unsigned char* bins_u8   = (unsigned char*)(blkoff + nblk * NBINS);

    k_hist   <<<nblk, 1024, 0, stream>>>(coords, hist, bins_u8, npts);
    k_scan   <<<1,    1024, 0, stream>>>(hist, blkoff, nblk);
    k_scatter<<<nblk, 1024, 0, stream>>>(bins_u8, blkoff, sorted_pk, npts);
    k_gemm   <<<npts / PPB, PPB, 0, stream>>>(feat, filt, bias, sorted_pk, out);
}

// Round 7
// 88.244 us; speedup vs baseline: 1.3696x; 1.0719x over previous
//
#include <hip/hip_runtime.h>

// GeodesicConv via counting-sort by filter bin; W broadcast from LDS;
// d-quad work split for occupancy.
//
// out[p,d] = sum_c feat[p,c] * filters[bin(p)][c][d] + bias[d], 40 bins.
//
// K4 k_gemm geometry (round-5 change): thread = (point, quad). 256-thread
// block covers 64 sorted points x 4 output-quads (8 d each). 4x the waves of
// round 4 (2048 blocks, up to 8 waves/SIMD at ~60 VGPR) to hide ds_read/FMA
// latency that left round-4 at ~2 waves/SIMD. Per ds_read_b128: 4 distinct
// addresses 32B apart -> conflict-free, 16-lane broadcast each.

#define NBINS 40
#define NB_MAX 4
#define PTS_BLK 64
#define MAX_NBLK 128

__device__ __forceinline__ int bin_of(float2 rc) {
    const float TWO_PI_F = (float)(2.0 * 3.14159);
    int ri = (int)(rc.x * 5.0f);
    ri = min(max(ri, 0), 4);
    int oi = (int)((rc.y * 8.0f) / TWO_PI_F);
    oi = min(max(oi, 0), 7);
    return ri * 8 + oi;
}

__global__ __launch_bounds__(1024)
void k_hist(const float2* __restrict__ coords, int* __restrict__ hist,
            unsigned char* __restrict__ bins_u8, int npts) {
    __shared__ int h[NBINS];
    const int tid = threadIdx.x;
    if (tid < NBINS) h[tid] = 0;
    __syncthreads();
    const int p = blockIdx.x * 1024 + tid;
    if (p < npts) {
        const int b = bin_of(coords[p]);
        bins_u8[p] = (unsigned char)b;
        atomicAdd(&h[b], 1);
    }
    __syncthreads();
    if (tid < NBINS) hist[blockIdx.x * NBINS + tid] = h[tid];
}

__global__ __launch_bounds__(1024)
void k_scan(const int* __restrict__ hist, int* __restrict__ blkoff, int nblk) {
    __shared__ int lh[MAX_NBLK * NBINS];
    __shared__ int btot[NBINS];
    __shared__ int base[NBINS];
    const int tid  = threadIdx.x;
    const int wave = tid >> 6;
    const int lane = tid & 63;
    for (int i = tid; i < nblk * NBINS; i += 1024) lh[i] = hist[i];
    __syncthreads();
    for (int b = wave; b < NBINS; b += 16) {     // one wave per bin
        int v0 = lh[lane * NBINS + b];
        int v1 = lh[(64 + lane) * NBINS + b];
        #pragma unroll
        for (int off = 1; off < 64; off <<= 1) { int t = __shfl_up(v0, off); if (lane >= off) v0 += t; }
        const int tot0 = __shfl(v0, 63);
        #pragma unroll
        for (int off = 1; off < 64; off <<= 1) { int t = __shfl_up(v1, off); if (lane >= off) v1 += t; }
        const int total = __shfl(v1, 63) + tot0;
        int e0 = __shfl_up(v0, 1); if (lane == 0) e0 = 0;
        int e1 = __shfl_up(v1, 1); if (lane == 0) e1 = 0;
        e1 += tot0;
        lh[lane * NBINS + b] = e0;
        lh[(64 + lane) * NBINS + b] = e1;
        if (lane == 0) btot[b] = total;
    }
    __syncthreads();
    if (wave == 0) {
        int v = (lane < NBINS) ? btot[lane] : 0;
        #pragma unroll
        for (int off = 1; off < 64; off <<= 1) { int t = __shfl_up(v, off); if (lane >= off) v += t; }
        int e = __shfl_up(v, 1); if (lane == 0) e = 0;
        if (lane < NBINS) base[lane] = e;
    }
    __syncthreads();
    for (int i = tid; i < nblk * NBINS; i += 1024) {
        const int b = i - (i / NBINS) * NBINS;
        blkoff[i] = lh[i] + base[b];
    }
}

__global__ __launch_bounds__(1024)
void k_scatter(const unsigned char* __restrict__ bins_u8, const int* __restrict__ blkoff,
               int* __restrict__ sorted_pk, int npts) {
    __shared__ int off[NBINS];
    __shared__ int cnt[NBINS];
    const int tid = threadIdx.x;
    if (tid < NBINS) { off[tid] = blkoff[blockIdx.x * NBINS + tid]; cnt[tid] = 0; }
    __syncthreads();
    const int p = blockIdx.x * 1024 + tid;
    if (p < npts) {
        const int b = (int)bins_u8[p];
        const int r = atomicAdd(&cnt[b], 1);
        sorted_pk[off[b] + r] = p | (b << 20);
    }
}

#define GEMM_BODY(W4EXPR)                                                     \
    unsigned long long rem = __ballot(1);                                     \
    while (rem) {                                                             \
        const int src = (int)__ffsll((long long)rem) - 1;                     \
        const int bb  = __shfl(b, src);                                       \
        const unsigned long long m = __ballot(b == bb);                       \
        rem &= ~m;                                                            \
        const bool act = (b == bb);                                           \
        const float4* __restrict__ W4 = (W4EXPR);                             \
        _Pragma("unroll")                                                     \
        for (int c = 0; c < 32; ++c) {                                        \
            const float fc = act ? f[c] : 0.0f;                               \
            const float4 w0 = W4[c * 8 + q * 2 + 0];                          \
            const float4 w1 = W4[c * 8 + q * 2 + 1];                          \
            acc[0] = fmaf(fc, w0.x, acc[0]);                                  \
            acc[1] = fmaf(fc, w0.y, acc[1]);                                  \
            acc[2] = fmaf(fc, w0.z, acc[2]);                                  \
            acc[3] = fmaf(fc, w0.w, acc[3]);                                  \
            acc[4] = fmaf(fc, w1.x, acc[4]);                                  \
            acc[5] = fmaf(fc, w1.y, acc[5]);                                  \
            acc[6] = fmaf(fc, w1.z, acc[6]);                                  \
            acc[7] = fmaf(fc, w1.w, acc[7]);                                  \
        }                                                                     \
    }

__global__ __launch_bounds__(256, 4)
void k_gemm(const float* __restrict__ feat, const float* __restrict__ filt,
            const float* __restrict__ bias, const int* __restrict__ sorted_pk,
            float* __restrict__ out) {
    __shared__ float4 Wl[NB_MAX * 256];          // up to 4 bins x 4 KB = 16 KB
    const int tid     = threadIdx.x;
    const int q       = tid & 3;                 // output quad (8 d-values)
    const int pl      = tid >> 2;                // point within block (0..63)
    const int blkbase = blockIdx.x * PTS_BLK;

    const int pk  = sorted_pk[blkbase + pl];
    const int idx = pk & 0xFFFFF;
    const int b   = pk >> 20;

    const int b0 = sorted_pk[blkbase] >> 20;            // block spans [b0,b1]
    const int b1 = sorted_pk[blkbase + PTS_BLK - 1] >> 20;
    const int nb = b1 - b0 + 1;

    const float4* __restrict__ filt4 = reinterpret_cast<const float4*>(filt);
    if (nb <= NB_MAX) {
        for (int i = tid; i < nb * 256; i += 256) Wl[i] = filt4[b0 * 256 + i];
    }
    __syncthreads();

    const float4* fp = reinterpret_cast<const float4*>(feat + (size_t)idx * 32);
    float f[32];
    #pragma unroll
    for (int g = 0; g < 8; ++g) {
        const float4 v = fp[g];
        f[g * 4 + 0] = v.x; f[g * 4 + 1] = v.y; f[g * 4 + 2] = v.z; f[g * 4 + 3] = v.w;
    }

    float acc[8];
    {
        const float4* bp = reinterpret_cast<const float4*>(bias) + q * 2;
        const float4 bv0 = bp[0], bv1 = bp[1];
        acc[0] = bv0.x; acc[1] = bv0.y; acc[2] = bv0.z; acc[3] = bv0.w;
        acc[4] = bv1.x; acc[5] = bv1.y; acc[6] = bv1.z; acc[7] = bv1.w;
    }

    if (nb <= NB_MAX) {              // hot path: W broadcast from LDS
        GEMM_BODY(&Wl[(bb - b0) * 256])
    } else {                         // never in practice (segments >> 64)
        GEMM_BODY(&filt4[(size_t)bb * 256])
    }

    float4* op = reinterpret_cast<float4*>(out + (size_t)idx * 32 + q * 8);
    op[0] = make_float4(acc[0], acc[1], acc[2], acc[3]);
    op[1] = make_float4(acc[4], acc[5], acc[6], acc[7]);
}

extern "C" void kernel_launch(void* const* d_in, const int* in_sizes, int n_in,
                              void* d_out, int out_size, void* d_ws, size_t ws_size,
                              hipStream_t stream) {
    const float*  feat   = (const float*)d_in[0];
    const float2* coords = (const float2*)d_in[1];
    const float*  filt   = (const float*)d_in[2];
    const float*  bias   = (const float*)d_in[3];
    float* out = (float*)d_out;

    const int npts = in_sizes[0] / 32;                   // 131072
    const int nblk = (npts + 1023) / 1024;               // 128

    int* sorted_pk           = (int*)d_ws;               // npts
    int* hist                = sorted_pk + npts;         // nblk*40
    int* blkoff              = hist + nblk * NBINS;      // nblk*40
    unsigned char* bins_u8   = (unsigned char*)(blkoff + nblk * NBINS);

    k_hist   <<<nblk, 1024, 0, stream>>>(coords, hist, bins_u8, npts);
    k_scan   <<<1,    1024, 0, stream>>>(hist, blkoff, nblk);
    k_scatter<<<nblk, 1024, 0, stream>>>(bins_u8, blkoff, sorted_pk, npts);
    k_gemm   <<<npts / PTS_BLK, 256, 0, stream>>>(feat, filt, bias, sorted_pk, out);
}